// Round 5
// baseline (146.856 us; speedup 1.0000x reference)
//
#include <hip/hip_runtime.h>
#include <stdint.h>

// ContinuousConvolution, MI355X gfx950. Round 15: knn 2-queries-per-wave.
// R14 post-mortem: Pass A load-chain fixes bought ~2us -> critical path is
// the two 21-step cross-lane sort networks (~30cy/step dependent ds_swizzle).
// Fix: each wave owns TWO sorted-adjacent queries; the tau sort and the
// final selection sort run as FUSED dual networks (2 independent chains
// interleaved -> 2x ILP on the latency path). Occupancy preserved by
// halving the LDS cache: allk stores 32-bit fordkey only; survivor sorted
// position reconstructed from the SGPR segment prefix table
// (ii = j + segS[u]-pre[u]). Overflow = upfront cnt0>CAPA (equivalent to
// R14's incremental check); CAPA 480 (+2.4 sigma, ~1% exact fallback).
// Survivor set / keys / tie-breaks bit-identical to R14.
// Build + mlp kernels unchanged.

typedef unsigned short u16;
typedef unsigned int   u32;
typedef unsigned long long u64;

#define NPTS  8192
#define KNB   16
#define SCAP  128   // survivors: E~20, n-independent
#define CAPA  480   // per-query LDS key-cache: box ~432 +- 20, +2.4 sigma
#define QPW   8

__device__ __forceinline__ float bf2f(u16 u) {
    union { u32 i; float f; } v; v.i = ((u32)u) << 16; return v.f;
}
__device__ __forceinline__ u16 f2bf(float f) {
    u32 x = __float_as_uint(f);
    return (u16)((x + 0x7FFFu + ((x >> 16) & 1u)) >> 16);  // RNE (lossless here)
}
__device__ __forceinline__ u32 fordkey(float f) {
    u32 u = __float_as_uint(f);
    return u ^ ((u32)((int)u >> 31) | 0x80000000u);
}
__device__ __forceinline__ u64 shflxor64(u64 v, int m) {
    int lo = __shfl_xor((int)(u32)v, m, 64);
    int hi = __shfl_xor((int)(u32)(v >> 32), m, 64);
    return ((u64)(u32)hi << 32) | (u32)lo;
}
// Wave-internal LDS fence (rule #18 idiom).
__device__ __forceinline__ void wave_fence() {
    asm volatile("s_waitcnt lgkmcnt(0)" ::: "memory");
    __builtin_amdgcn_sched_barrier(0);
}
// Reference-matching d2 (verified round 5): dot = Eigen FMA chain, rest strict.
__device__ __forceinline__ float sq_np32(float x, float y, float z) {
    return __fadd_rn(__fadd_rn(__fmul_rn(x, x), __fmul_rn(y, y)), __fmul_rn(z, z));
}
__device__ __forceinline__ float d2_ref(float qx, float qy, float qz, float qsq,
                                        float x, float y, float z, float sq) {
    float dot = fmaf(z, qz, fmaf(y, qy, __fmul_rn(x, qx)));
    return __fsub_rn(__fadd_rn(qsq, sq), __fmul_rn(2.0f, dot));
}
__device__ __forceinline__ int cellof(float v) {
    int c = (int)floorf(v * 8.0f);
    return c < 0 ? 0 : (c > 7 ? 7 : c);
}

// ---------------- build kernels ----------------
__global__ __launch_bounds__(256) void pack_count_kernel(
    const float* __restrict__ pf, const float* __restrict__ coords,
    u16* __restrict__ pfh, int* __restrict__ counts) {
    int gid = blockIdx.x * 256 + threadIdx.x;     // 0..1048575
    pfh[gid] = f2bf(pf[gid]);
    if (gid < 2 * NPTS) {
        float x = coords[gid * 3 + 0];
        float y = coords[gid * 3 + 1];
        float z = coords[gid * 3 + 2];
        int b = gid >> 13;
        int cell = (cellof(x) * 8 + cellof(y)) * 8 + cellof(z);
        atomicAdd(&counts[b * 512 + cell], 1);
    }
}

__global__ __launch_bounds__(512) void scan_kernel(
    const int* __restrict__ counts, int* __restrict__ cellStart,
    int* __restrict__ cellOffset) {
    __shared__ int s[512];
    int b = blockIdx.x, t = threadIdx.x;
    int myc = counts[b * 512 + t];
    s[t] = myc; __syncthreads();
#pragma unroll
    for (int off = 1; off < 512; off <<= 1) {
        int v = (t >= off) ? s[t - off] : 0; __syncthreads();
        s[t] += v; __syncthreads();
    }
    int excl = s[t] - myc;
    cellStart[b * 513 + t] = excl;
    cellOffset[b * 512 + t] = excl;
    if (t == 511) cellStart[b * 513 + 512] = s[511];
}

__global__ __launch_bounds__(256) void scatter_kernel(
    const float* __restrict__ coords, int* __restrict__ cellOffset,
    float4* __restrict__ spts, int* __restrict__ sidx) {
    int gid = blockIdx.x * 256 + threadIdx.x;     // 0..16383
    float x = coords[gid * 3 + 0];
    float y = coords[gid * 3 + 1];
    float z = coords[gid * 3 + 2];
    int b = gid >> 13, i = gid & (NPTS - 1);
    int cell = (cellof(x) * 8 + cellof(y)) * 8 + cellof(z);
    int pos = atomicAdd(&cellOffset[b * 512 + cell], 1);
    spts[b * NPTS + pos] = make_float4(x, y, z, sq_np32(x, y, z));
    sidx[b * NPTS + pos] = i;
}

// Stream global points of cells [z0..z1] in column `base`, compact survivors
// (d2 <= tau) into surv as (fordkey(d2)<<32 | sorted_pos).
__device__ __forceinline__ void scan_seg(
    const float4* __restrict__ sp, const int* __restrict__ cs,
    u64* __restrict__ surv, int base, int z0, int z1,
    float qx, float qy, float qz, float qsq, float tau, int lane, int& cnt) {
    if (z0 > z1) return;
    int s = cs[base + z0], e = cs[base + z1 + 1];
    for (int i0 = s; i0 < e; i0 += 64) {
        int i = i0 + lane;
        bool valid = (i < e);
        int ii = valid ? i : (e - 1);       // clamp: no OOB
        float4 c = sp[ii];
        float d2 = d2_ref(qx, qy, qz, qsq, c.x, c.y, c.z, c.w);
        bool pass = valid && (d2 <= tau);
        u64 mask = __ballot(pass);
        if (pass) {
            int pre = __builtin_amdgcn_mbcnt_hi((u32)(mask >> 32),
                      __builtin_amdgcn_mbcnt_lo((u32)mask, 0));
            int pos = cnt + pre;
            if (pos < SCAP)
                surv[pos] = ((u64)fordkey(d2) << 32) | (u32)ii;
        }
        cnt += (int)__popcll(mask);         // uniform across wave
    }
}

// Segment table for the 3x3x3 box around cell (ucx,ucy,[az0..az1]).
// segS/segE = sorted-array ranges (masked to 0 when column OOB), pre =
// exclusive prefix of segment sizes (cache layout), cnt0 = total.
__device__ __forceinline__ void segtab(
    const int* __restrict__ cs, int ucx, int ucy, int az0, int az1,
    int* segS, int* segE, int* pre, int& cnt0) {
    int run = 0;
#pragma unroll
    for (int u = 0; u < 9; ++u) {
        int cx = ucx - 1 + (u / 3);
        int cy = ucy - 1 + (u % 3);
        bool ok = (cx >= 0) && (cx <= 7) && (cy >= 0) && (cy <= 7);
        int s = 0, e = 0;
        if (ok) {
            int base = (cx * 8 + cy) * 8;
            s = cs[base + az0];
            e = cs[base + az1 + 1];
        }
        segS[u] = s; segE[u] = e; pre[u] = run;
        run += e - s;
    }
    cnt0 = run;
}

// Pass A for one query: stream the box, lane-minima for tau, cache 32-bit
// keys at stream position pre[u]+(i-segS[u]) when !ovf.
__device__ __forceinline__ void passA_one(
    const float4* __restrict__ sp, u32* __restrict__ allk, int lane,
    float qx, float qy, float qz, float qsq,
    const int* segS, const int* segE, const int* pre, bool ovf,
    float& dmin) {
#pragma unroll
    for (int u = 0; u < 9; ++u) {
        int s = segS[u], e = segE[u];
        int cb = pre[u] - s;                  // cache idx = cb + i
#pragma unroll 1
        for (int i0 = s; i0 < e; i0 += 64) {
            int i = i0 + lane;
            bool valid = (i < e);
            int ii = valid ? i : (e - 1);     // clamp: no OOB
            float4 c = sp[ii];
            float d2 = d2_ref(qx, qy, qz, qsq, c.x, c.y, c.z, c.w);
            if (valid) {
                dmin = fminf(dmin, d2);
                if (!ovf) allk[cb + i] = fordkey(d2);
            }
        }
    }
}

// Filter from the key cache; position reconstructed from the prefix table:
// ii = j + (segS[u]-pre[u]) for the largest u with pre[u] <= j.
__device__ __forceinline__ int filter_lds(
    const u32* __restrict__ allk, u64* __restrict__ surv,
    const int* segS, const int* pre, int cnt0, u32 taukey, int lane) {
    int cnt = 0;
    for (int i0 = 0; i0 < cnt0; i0 += 64) {
        int j = i0 + lane;
        bool valid = (j < cnt0);
        u32 kk = valid ? allk[j] : 0xffffffffu;
        bool pass = valid && (kk <= taukey);
        int off = segS[0];                    // pre[0] == 0
#pragma unroll
        for (int u = 1; u < 9; ++u)
            off = (j >= pre[u]) ? (segS[u] - pre[u]) : off;
        int ii = j + off;
        u64 mask = __ballot(pass);
        if (pass) {
            int pc = __builtin_amdgcn_mbcnt_hi((u32)(mask >> 32),
                     __builtin_amdgcn_mbcnt_lo((u32)mask, 0));
            int pos = cnt + pc;
            if (pos < SCAP) surv[pos] = ((u64)kk << 32) | (u32)ii;
        }
        cnt += (int)__popcll(mask);
    }
    return cnt;
}

// B-box cells not covered by the LDS cache (normally none; full box on ovf).
__device__ __forceinline__ void bbox_scan(
    const float4* __restrict__ sp, const int* __restrict__ cs,
    u64* __restrict__ surv,
    float qx, float qy, float qz, float qsq, float tau,
    int ax0, int ax1, int ay0, int ay1, int az0, int az1, bool ovf,
    int lane, int& cnt) {
    float rr = sqrtf(tau + 1e-5f) + 1e-6f;
    int bx0 = max((int)floorf((qx - rr) * 8.0f), 0);
    int bx1 = min((int)floorf((qx + rr) * 8.0f), 7);
    int by0 = max((int)floorf((qy - rr) * 8.0f), 0);
    int by1 = min((int)floorf((qy + rr) * 8.0f), 7);
    int bz0 = max((int)floorf((qz - rr) * 8.0f), 0);
    int bz1 = min((int)floorf((qz + rr) * 8.0f), 7);
#pragma unroll 1
    for (int cx = bx0; cx <= bx1; ++cx)
#pragma unroll 1
        for (int cy = by0; cy <= by1; ++cy) {
            int base = (cx * 8 + cy) * 8;
            bool colInA = !ovf && cx >= ax0 && cx <= ax1 &&
                          cy >= ay0 && cy <= ay1;
            if (colInA) {
                scan_seg(sp, cs, surv, base, bz0, min(az0 - 1, bz1),
                         qx, qy, qz, qsq, tau, lane, cnt);
                scan_seg(sp, cs, surv, base, max(az1 + 1, bz0), bz1,
                         qx, qy, qz, qsq, tau, lane, cnt);
            } else {
                scan_seg(sp, cs, surv, base, bz0, bz1,
                         qx, qy, qz, qsq, tau, lane, cnt);
            }
        }
}

// R14 selection (single query): lex (key,payload) bitonic when cnt<=64,
// else 16-round min-extract over 128 survivors. Bit-identical to R12 u64.
__device__ __forceinline__ int sel_one(const u64* __restrict__ surv,
                                       int cnt, int lane) {
    int myidx = 0;
    if (cnt <= 64) {
        u32 k32 = 0xffffffffu, p32 = 0xffffffffu;
        if (lane < cnt) {
            u64 kk = surv[lane];
            k32 = (u32)(kk >> 32);
            p32 = (u32)kk;
        }
#pragma unroll
        for (int k = 2; k <= 64; k <<= 1) {
#pragma unroll
            for (int j2 = k >> 1; j2 >= 1; j2 >>= 1) {
                u32 ok = (u32)__shfl_xor((int)k32, j2, 64);
                u32 op = (u32)__shfl_xor((int)p32, j2, 64);
                bool lo = (lane & j2) == 0;
                bool up = (lane & k) == 0;
                bool takemin = (lo == up);
                bool less = (ok < k32) || (ok == k32 && op < p32);
                bool take = (less == takemin);
                k32 = take ? ok : k32;
                p32 = take ? op : p32;
            }
        }
        myidx = (int)p32;
    } else {
        int cc = cnt > SCAP ? SCAP : cnt;
        u64 a0 = (lane < cc) ? surv[lane] : ~0ull;
        u64 a1 = (64 + lane < cc) ? surv[64 + lane] : ~0ull;
        if (a1 < a0) { u64 tmp = a0; a0 = a1; a1 = tmp; }
#pragma unroll 1
        for (int r = 0; r < 16; ++r) {
            u64 m = a0;
#pragma unroll
            for (int d = 1; d < 64; d <<= 1) {
                u64 o = shflxor64(m, d);
                m = (o < m) ? o : m;
            }
            if (a0 == m) { a0 = a1; a1 = ~0ull; }
            if (lane == r) myidx = (int)(u32)(m & 0xffffffffu);
        }
    }
    return myidx;
}

// ---------------- Kernel A: grid knn (2 queries per wave, fused sorts) -----
__global__ __launch_bounds__(256, 6) void knn_kernel(
    const float4* __restrict__ spts, const int* __restrict__ sidx,
    const int* __restrict__ cellStart, int* __restrict__ idx_out) {
    __shared__ u32 allk_s[4][2][CAPA];     // 15360 B
    __shared__ u64 surv_s[4][2][SCAP];     //  8192 B

    const int lane = threadIdx.x & 63;
    const int wid  = threadIdx.x >> 6;
    u32* __restrict__ allkA = allk_s[wid][0];
    u32* __restrict__ allkB = allk_s[wid][1];
    u64* __restrict__ survA = surv_s[wid][0];
    u64* __restrict__ survB = surv_s[wid][1];

    const int blk  = blockIdx.x;               // 0..2047
    // XCD chunk swizzle (grid 2048 = 8 * 256).
    const int sblk = (blk & 7) * 256 + (blk >> 3);
    const int pg   = sblk * 8 + wid * 2;       // sorted position of query A
    const int b    = pg >> 13;                 // batch (block never straddles)
    const float4* sp = spts + b * NPTS;
    const int*    si = sidx + b * NPTS;
    const int*    cs = cellStart + b * 513;
    const int plA = pg & (NPTS - 1);
    const int plB = plA + 1;

    float4 qcA = sp[plA];
    float4 qcB = sp[plB];
    const float qxA = qcA.x, qyA = qcA.y, qzA = qcA.z, qsA = qcA.w;
    const float qxB = qcB.x, qyB = qcB.y, qzB = qcB.z, qsB = qcB.w;

    // Wave-uniform cell coords -> scalar domain (segment lookups = s_loads).
    const int uxA = __builtin_amdgcn_readfirstlane(cellof(qxA));
    const int uyA = __builtin_amdgcn_readfirstlane(cellof(qyA));
    const int uzA = __builtin_amdgcn_readfirstlane(cellof(qzA));
    const int uxB = __builtin_amdgcn_readfirstlane(cellof(qxB));
    const int uyB = __builtin_amdgcn_readfirstlane(cellof(qyB));
    const int uzB = __builtin_amdgcn_readfirstlane(cellof(qzB));

    const int axA0 = max(uxA - 1, 0), axA1 = min(uxA + 1, 7);
    const int ayA0 = max(uyA - 1, 0), ayA1 = min(uyA + 1, 7);
    const int azA0 = max(uzA - 1, 0), azA1 = min(uzA + 1, 7);
    const int axB0 = max(uxB - 1, 0), axB1 = min(uxB + 1, 7);
    const int ayB0 = max(uyB - 1, 0), ayB1 = min(uyB + 1, 7);
    const int azB0 = max(uzB - 1, 0), azB1 = min(uzB + 1, 7);

    int segSA[9], segEA[9], preA[9], cnt0A;
    int segSB[9], segEB[9], preB[9], cnt0B;
    segtab(cs, uxA, uyA, azA0, azA1, segSA, segEA, preA, cnt0A);
    segtab(cs, uxB, uyB, azB0, azB1, segSB, segEB, preB, cnt0B);
    const bool ovfA = cnt0A > CAPA;   // == R14's incremental overflow check
    const bool ovfB = cnt0B > CAPA;

    float dminA = 3.0e38f, dminB = 3.0e38f;
    passA_one(sp, allkA, lane, qxA, qyA, qzA, qsA, segSA, segEA, preA, ovfA, dminA);
    passA_one(sp, allkB, lane, qxB, qyB, qzB, qsB, segSB, segEB, preB, ovfB, dminB);
    wave_fence();   // key caches visible before filter

    // FUSED dual bitonic sort-64 over lane minima (2 independent networks).
    float vA = dminA, vB = dminB;
#pragma unroll
    for (int k = 2; k <= 64; k <<= 1) {
#pragma unroll
        for (int j2 = k >> 1; j2 >= 1; j2 >>= 1) {
            float oA = __shfl_xor(vA, j2, 64);
            float oB = __shfl_xor(vB, j2, 64);
            bool lo = (lane & j2) == 0;
            bool up = (lane & k) == 0;
            bool tm = (lo == up);
            float mnA = fminf(vA, oA), mxA = fmaxf(vA, oA);
            float mnB = fminf(vB, oB), mxB = fmaxf(vB, oB);
            vA = tm ? mnA : mxA;
            vB = tm ? mnB : mxB;
        }
    }
    const float tauA = __shfl(vA, 15, 64);   // 16th smallest lane-min
    const float tauB = __shfl(vB, 15, 64);

    int cntA = 0, cntB = 0;
    if (!ovfA) cntA = filter_lds(allkA, survA, segSA, preA, cnt0A,
                                 fordkey(tauA), lane);
    if (!ovfB) cntB = filter_lds(allkB, survB, segSB, preB, cnt0B,
                                 fordkey(tauB), lane);
    bbox_scan(sp, cs, survA, qxA, qyA, qzA, qsA, tauA,
              axA0, axA1, ayA0, ayA1, azA0, azA1, ovfA, lane, cntA);
    bbox_scan(sp, cs, survB, qxB, qyB, qzB, qsB, tauB,
              axB0, axB1, ayB0, ayB1, azB0, azB1, ovfB, lane, cntB);
    wave_fence();   // survivors visible

    int myA, myB;
    if (cntA <= 64 && cntB <= 64) {
        // FUSED dual (key,payload) lex bitonic — same compare as R14.
        u32 kA = 0xffffffffu, pA = 0xffffffffu;
        u32 kB = 0xffffffffu, pB = 0xffffffffu;
        if (lane < cntA) { u64 kk = survA[lane]; kA = (u32)(kk >> 32); pA = (u32)kk; }
        if (lane < cntB) { u64 kk = survB[lane]; kB = (u32)(kk >> 32); pB = (u32)kk; }
#pragma unroll
        for (int k = 2; k <= 64; k <<= 1) {
#pragma unroll
            for (int j2 = k >> 1; j2 >= 1; j2 >>= 1) {
                u32 okA = (u32)__shfl_xor((int)kA, j2, 64);
                u32 opA = (u32)__shfl_xor((int)pA, j2, 64);
                u32 okB = (u32)__shfl_xor((int)kB, j2, 64);
                u32 opB = (u32)__shfl_xor((int)pB, j2, 64);
                bool lo = (lane & j2) == 0;
                bool up = (lane & k) == 0;
                bool tm = (lo == up);
                bool lessA = (okA < kA) || (okA == kA && opA < pA);
                bool takeA = (lessA == tm);
                kA = takeA ? okA : kA;
                pA = takeA ? opA : pA;
                bool lessB = (okB < kB) || (okB == kB && opB < pB);
                bool takeB = (lessB == tm);
                kB = takeB ? okB : kB;
                pB = takeB ? opB : pB;
            }
        }
        myA = (int)pA;
        myB = (int)pB;
    } else {
        myA = sel_one(survA, cntA, lane);
        myB = sel_one(survB, cntB, lane);
    }

    if (lane < KNB) {
        const int qA = si[plA];
        idx_out[((size_t)b * NPTS + qA) * KNB + lane] = si[myA & (NPTS - 1)];
        const int qB = si[plB];
        idx_out[((size_t)b * NPTS + qB) * KNB + lane] = si[myB & (NPTS - 1)];
    }
}

// ---------------- Kernel B: gather + collapsed MLP, sorted order ----------------
// grid 2048 (= 8 XCD chunks x 256). Swizzle: hardware round-robins blk%8 -> XCD,
// so sblk = (blk&7)*256 + blk>>3 gives each XCD a CONTIGUOUS sorted-query chunk
// -> neighbor gathers hit that XCD's L2 (working set ~0.5 MB + halo << 4 MB).
__global__ __launch_bounds__(64) void mlp_kernel(
    const u16* __restrict__ pfh, const float* __restrict__ coords,
    const float* __restrict__ w1, const float* __restrict__ b1,
    const float* __restrict__ w2, const float* __restrict__ b2,
    const float* __restrict__ w3, const float* __restrict__ b3,
    const float* __restrict__ aw, const float* __restrict__ ab,
    const int* __restrict__ knn_idx, const int* __restrict__ sidx,
    float* __restrict__ out) {

    __shared__ __attribute__((aligned(16))) float vbuf[2][68];
    __shared__ __attribute__((aligned(16))) float h1buf[2][36];

    const int lane = threadIdx.x;            // 0..63
    const int r    = lane & 31;
    const int vec  = lane >> 5;

    float w1r[68];
#pragma unroll
    for (int c = 0; c < 67; ++c) w1r[c] = w1[r * 67 + c];
    w1r[67] = 0.0f;
    float w2r[32];
    {
        const float4* p = (const float4*)(w2 + lane * 32);
#pragma unroll
        for (int c4 = 0; c4 < 8; ++c4) {
            float4 v = p[c4];
            w2r[c4 * 4 + 0] = v.x; w2r[c4 * 4 + 1] = v.y;
            w2r[c4 * 4 + 2] = v.z; w2r[c4 * 4 + 3] = v.w;
        }
    }
    float w3r[64];
    {
        const float4* p = (const float4*)(w3 + lane * 64);
#pragma unroll
        for (int c4 = 0; c4 < 16; ++c4) {
            float4 v = p[c4];
            w3r[c4 * 4 + 0] = v.x; w3r[c4 * 4 + 1] = v.y;
            w3r[c4 * 4 + 2] = v.z; w3r[c4 * 4 + 3] = v.w;
        }
    }
    float awr[16];
#pragma unroll
    for (int k = 0; k < 16; ++k) awr[k] = aw[k];
    float sa = 0.0f;
#pragma unroll
    for (int k = 0; k < 16; ++k) sa += awr[k];
    const float b1v = b1[r], b2v = b2[lane], b3v = b3[lane], abv = ab[0];
    const float c1 = (vec == 0) ? 16.0f : sa;

    // XCD-chunk swizzle (grid = 2048 = 8 * 256)
    const int sblk = (blockIdx.x & 7) * 256 + (blockIdx.x >> 3);

#pragma unroll 1
    for (int t = 0; t < QPW; ++t) {
        const int gp = sblk * QPW + t;        // global sorted position 0..16383
        const int b  = gp >> 13;
        const int q  = sidx[(size_t)b * NPTS + (gp & (NPTS - 1))];  // original id
        const int gq = b * NPTS + q;          // output/knn row
        const u16*   pfb = pfh + (size_t)b * NPTS * 64;
        const float* cb  = coords + (size_t)b * NPTS * 3;

        int myi = knn_idx[(size_t)gq * KNB + (lane & 15)] & (NPTS - 1);

        float pool = -3.0e38f, G1 = 0.0f, Ga = 0.0f;
#pragma unroll
        for (int k = 0; k < 16; ++k) {
            int nk = __shfl(myi, k, 64);
            float v = bf2f(pfb[nk * 64 + lane]);
            pool = fmaxf(pool, v);
            G1 += v;
            Ga = fmaf(awr[k], v, Ga);
        }
        vbuf[0][lane] = G1;
        vbuf[1][lane] = Ga;

        if (lane < 48) {
            int j  = lane >> 4;
            int i0 = __shfl(myi, 0, 64);
            float rel  = cb[myi * 3 + j] - cb[i0 * 3 + j];
            float wrel = awr[lane & 15] * rel;
#pragma unroll
            for (int d = 1; d < 16; d <<= 1) {
                rel  += __shfl_xor(rel, d, 64);
                wrel += __shfl_xor(wrel, d, 64);
            }
            if ((lane & 15) == 0) { vbuf[0][64 + j] = rel; vbuf[1][64 + j] = wrel; }
        }
        if (lane == 0) { vbuf[0][67] = 0.0f; vbuf[1][67] = 0.0f; }
        __syncthreads();

        float acc = c1 * b1v;
        {
            const float4* vp = (const float4*)(&vbuf[vec][0]);
#pragma unroll
            for (int c4 = 0; c4 < 17; ++c4) {
                float4 g4 = vp[c4];
                acc = fmaf(g4.x, w1r[c4 * 4 + 0], acc);
                acc = fmaf(g4.y, w1r[c4 * 4 + 1], acc);
                acc = fmaf(g4.z, w1r[c4 * 4 + 2], acc);
                acc = fmaf(g4.w, w1r[c4 * 4 + 3], acc);
            }
        }
        h1buf[vec][r] = acc;
        __syncthreads();

        float a0 = 16.0f * b2v, a1 = sa * b2v;
        {
            const float4* p0 = (const float4*)(&h1buf[0][0]);
            const float4* p1 = (const float4*)(&h1buf[1][0]);
#pragma unroll
            for (int c4 = 0; c4 < 8; ++c4) {
                float4 x0 = p0[c4], x1 = p1[c4];
                a0 = fmaf(x0.x, w2r[c4 * 4 + 0], a0);
                a0 = fmaf(x0.y, w2r[c4 * 4 + 1], a0);
                a0 = fmaf(x0.z, w2r[c4 * 4 + 2], a0);
                a0 = fmaf(x0.w, w2r[c4 * 4 + 3], a0);
                a1 = fmaf(x1.x, w2r[c4 * 4 + 0], a1);
                a1 = fmaf(x1.y, w2r[c4 * 4 + 1], a1);
                a1 = fmaf(x1.z, w2r[c4 * 4 + 2], a1);
                a1 = fmaf(x1.w, w2r[c4 * 4 + 3], a1);
            }
        }
        __syncthreads();
        vbuf[0][lane] = a0;
        vbuf[1][lane] = a1;
        __syncthreads();

        float s1 = 16.0f * b3v, sA = sa * b3v;
        {
            const float4* p0 = (const float4*)(&vbuf[0][0]);
            const float4* p1 = (const float4*)(&vbuf[1][0]);
#pragma unroll
            for (int c4 = 0; c4 < 16; ++c4) {
                float4 x0 = p0[c4], x1 = p1[c4];
                s1 = fmaf(x0.x, w3r[c4 * 4 + 0], s1);
                s1 = fmaf(x0.y, w3r[c4 * 4 + 1], s1);
                s1 = fmaf(x0.z, w3r[c4 * 4 + 2], s1);
                s1 = fmaf(x0.w, w3r[c4 * 4 + 3], s1);
                sA = fmaf(x1.x, w3r[c4 * 4 + 0], sA);
                sA = fmaf(x1.y, w3r[c4 * 4 + 1], sA);
                sA = fmaf(x1.z, w3r[c4 * 4 + 2], sA);
                sA = fmaf(x1.w, w3r[c4 * 4 + 3], sA);
            }
        }
        float* op = out + (size_t)gq * 192;
        op[lane]       = s1;
        op[64 + lane]  = pool;
        op[128 + lane] = sA + abv;
        __syncthreads();
    }
}

extern "C" void kernel_launch(void* const* d_in, const int* in_sizes, int n_in,
                              void* d_out, int out_size, void* d_ws, size_t ws_size,
                              hipStream_t stream) {
    const float* pf     = (const float*)d_in[0];
    const float* coords = (const float*)d_in[1];
    const float* w1     = (const float*)d_in[2];
    const float* b1     = (const float*)d_in[3];
    const float* w2     = (const float*)d_in[4];
    const float* b2     = (const float*)d_in[5];
    const float* w3     = (const float*)d_in[6];
    const float* b3     = (const float*)d_in[7];
    const float* aw     = (const float*)d_in[8];
    const float* ab     = (const float*)d_in[9];

    char* ws = (char*)d_ws;
    int*    knn_idx    = (int*)ws;                              // 1 MB
    u16*    pfh        = (u16*)(ws + (1 << 20));                // 2 MB
    float4* spts       = (float4*)(ws + (3 << 20));             // 256 KB
    int*    sidx       = (int*)(ws + (3 << 20) + (256 << 10));  // 64 KB
    int*    cellStart  = (int*)(ws + (3 << 20) + (320 << 10));  // 2*513*4 B
    int*    counts     = (int*)(ws + (3 << 20) + (328 << 10));  // 2*512*4 B
    int*    cellOffset = (int*)(ws + (3 << 20) + (336 << 10));  // 2*512*4 B
    float*  outp       = (float*)d_out;

    hipMemsetAsync(counts, 0, 2 * 512 * sizeof(int), stream);
    pack_count_kernel<<<4096, 256, 0, stream>>>(pf, coords, pfh, counts);
    scan_kernel<<<2, 512, 0, stream>>>(counts, cellStart, cellOffset);
    scatter_kernel<<<64, 256, 0, stream>>>(coords, cellOffset, spts, sidx);
    knn_kernel<<<2048, 256, 0, stream>>>(spts, sidx, cellStart, knn_idx);
    mlp_kernel<<<2048, 64, 0, stream>>>(pfh, coords, w1, b1, w2, b2, w3, b3,
                                        aw, ab, knn_idx, sidx, outp);
}